// Round 1
// baseline (159.272 us; speedup 1.0000x reference)
//
#include <hip/hip_runtime.h>

// Problem constants
#define BATCH 8
#define HW_N  1024   // 32*32
#define CD    128    // channels
#define W_IMG 32
#define CH_O  30
#define F_N   900    // 30*30

// Workspace layout (bytes)
#define OFF_Q   0u
#define OFF_K   4194304u            // 8192*128*4
#define OFF_V   8388608u
#define OFF_D   8421376u            // V ends at 8388608+32768
#define OFF_T   9240576u            // D ends at 8421376+819200
#define OFF_TV  9306112u            // T: 8192 doubles = 65536 B
// total: 9371648 bytes

// -------------------------------------------------------------------------
// Kernel A: Q = xf@Wq^T + bq ; K = xf@Wk^T + bk ; V = xf@wv + bv
// grid 256 blocks x 256 threads; each block does 32 rows.
// -------------------------------------------------------------------------
__global__ __launch_bounds__(256) void qkv_kernel(
    const float* __restrict__ xf,
    const float* __restrict__ Wq, const float* __restrict__ bq,
    const float* __restrict__ Wk, const float* __restrict__ bk,
    const float* __restrict__ wv, const float* __restrict__ bv,
    float* __restrict__ Q, float* __restrict__ Kf, float* __restrict__ V)
{
    __shared__ float xs[32][132];
    __shared__ float wqs[32][132];
    __shared__ float wks[32][132];
    const int t = threadIdx.x;
    const int rowbase = blockIdx.x * 32;

    // stage 32x128 input rows
#pragma unroll
    for (int m = 0; m < 4; ++m) {
        int id = t + 256 * m;          // 0..1023 float4 slots
        int r  = id >> 5;
        int kq = id & 31;
        *(float4*)&xs[r][kq * 4] =
            *(const float4*)&xf[(rowbase + r) * CD + kq * 4];
    }

    const int tx = t & 15, ty = t >> 4;

    for (int cc = 0; cc < 4; ++cc) {   // 4 chunks of 32 output cols
        __syncthreads();               // covers xs (cc=0) and wqs reuse
#pragma unroll
        for (int m = 0; m < 4; ++m) {
            int id = t + 256 * m;
            int r  = id >> 5;
            int kq = id & 31;
            *(float4*)&wqs[r][kq * 4] =
                *(const float4*)&Wq[(cc * 32 + r) * CD + kq * 4];
            *(float4*)&wks[r][kq * 4] =
                *(const float4*)&Wk[(cc * 32 + r) * CD + kq * 4];
        }
        __syncthreads();

        float aq[2][2], ak[2][2];
#pragma unroll
        for (int j = 0; j < 2; ++j)
#pragma unroll
            for (int m = 0; m < 2; ++m) { aq[j][m] = 0.f; ak[j][m] = 0.f; }

#pragma unroll 8
        for (int k = 0; k < CD; k += 4) {
            float4 x[2], q[2], kk[2];
            x[0]  = *(const float4*)&xs[ty][k];
            x[1]  = *(const float4*)&xs[ty + 16][k];
            q[0]  = *(const float4*)&wqs[tx][k];
            q[1]  = *(const float4*)&wqs[tx + 16][k];
            kk[0] = *(const float4*)&wks[tx][k];
            kk[1] = *(const float4*)&wks[tx + 16][k];
#pragma unroll
            for (int j = 0; j < 2; ++j)
#pragma unroll
                for (int m = 0; m < 2; ++m) {
                    aq[j][m] += x[j].x * q[m].x + x[j].y * q[m].y +
                                x[j].z * q[m].z + x[j].w * q[m].w;
                    ak[j][m] += x[j].x * kk[m].x + x[j].y * kk[m].y +
                                x[j].z * kk[m].z + x[j].w * kk[m].w;
                }
        }

#pragma unroll
        for (int j = 0; j < 2; ++j)
#pragma unroll
            for (int m = 0; m < 2; ++m) {
                int r = ty + 16 * j;
                int c = cc * 32 + tx + 16 * m;
                Q[(rowbase + r) * CD + c]  = aq[j][m] + bq[c];
                Kf[(rowbase + r) * CD + c] = ak[j][m] + bk[c];
            }
    }

    __syncthreads();
    if (t < 32) {
        float s = 0.f;
#pragma unroll 8
        for (int k = 0; k < CD; ++k) s += xs[t][k] * wv[k];
        V[rowbase + t] = s + bv[0];
    }
}

// -------------------------------------------------------------------------
// Kernel B: S = Q@K^T fused with exp, row sums (double), banded E store.
// grid (8, 32, 4): batch x 32-row-block x 256-col-chunk; 256 threads.
// -------------------------------------------------------------------------
__global__ __launch_bounds__(256) void attn_s_kernel(
    const float* __restrict__ Q, const float* __restrict__ Kf,
    const float* __restrict__ V,
    double* __restrict__ T, double* __restrict__ TV,
    float* __restrict__ D)
{
    const int b  = blockIdx.x;
    const int rb = blockIdx.y;
    const int cc = blockIdx.z;

    __shared__ float  Qs[32][132];
    __shared__ float  Ks[64][132];
    __shared__ float  Vs[64];
    __shared__ double redd[32][17];

    const int t  = threadIdx.x;
    const int tx = t & 15, ty = t >> 4;
    const int rowflat = b * HW_N + rb * 32;

#pragma unroll
    for (int m = 0; m < 4; ++m) {
        int id = t + 256 * m;
        int r  = id >> 5;
        int kq = id & 31;
        *(float4*)&Qs[r][kq * 4] =
            *(const float4*)&Q[(rowflat + r) * CD + kq * 4];
    }

    double ts[2]  = {0.0, 0.0};
    double tvs[2] = {0.0, 0.0};

    for (int ct = 0; ct < 4; ++ct) {
        const int colbase = cc * 256 + ct * 64;
        __syncthreads();
#pragma unroll
        for (int m = 0; m < 8; ++m) {
            int id = t + 256 * m;
            int c  = id >> 5;
            int kq = id & 31;
            *(float4*)&Ks[c][kq * 4] =
                *(const float4*)&Kf[(b * HW_N + colbase + c) * CD + kq * 4];
        }
        if (t < 64) Vs[t] = V[b * HW_N + colbase + t];
        __syncthreads();

        float acc[2][4];
#pragma unroll
        for (int j = 0; j < 2; ++j)
#pragma unroll
            for (int m = 0; m < 4; ++m) acc[j][m] = 0.f;

#pragma unroll 8
        for (int k = 0; k < CD; k += 4) {
            float4 a[2], bb[4];
            a[0]  = *(const float4*)&Qs[ty][k];
            a[1]  = *(const float4*)&Qs[ty + 16][k];
            bb[0] = *(const float4*)&Ks[tx][k];
            bb[1] = *(const float4*)&Ks[tx + 16][k];
            bb[2] = *(const float4*)&Ks[tx + 32][k];
            bb[3] = *(const float4*)&Ks[tx + 48][k];
#pragma unroll
            for (int j = 0; j < 2; ++j)
#pragma unroll
                for (int m = 0; m < 4; ++m)
                    acc[j][m] += a[j].x * bb[m].x + a[j].y * bb[m].y +
                                 a[j].z * bb[m].z + a[j].w * bb[m].w;
        }

        // epilogue: exp, accumulate sums, banded store
#pragma unroll
        for (int j = 0; j < 2; ++j) {
            const int hw_r = rb * 32 + ty + 16 * j;
#pragma unroll
            for (int m = 0; m < 4; ++m) {
                const int cl   = tx + 16 * m;
                const int hw_c = colbase + cl;
                float e = __expf(acc[j][m]);
                ts[j] += (double)e;
                float ev = e * Vs[cl];          // fp32 product, matched in kernel C
                tvs[j] += (double)ev;
                int dy = (hw_c >> 5) - (hw_r >> 5);
                int dx = (hw_c & 31) - (hw_r & 31);
                if ((unsigned)(dy + 2) <= 4u && (unsigned)(dx + 2) <= 4u)
                    D[(b * HW_N + hw_r) * 25 + (dy + 2) * 5 + (dx + 2)] = e;
            }
        }
    }

    // block reduction across tx, then device atomics (4 col-chunk blocks/row)
    __syncthreads();
    redd[ty][tx]      = ts[0];
    redd[ty + 16][tx] = ts[1];
    __syncthreads();
    if (t < 32) {
        double s = 0.0;
#pragma unroll
        for (int x = 0; x < 16; ++x) s += redd[t][x];
        atomicAdd(&T[rowflat + t], s);
    }
    __syncthreads();
    redd[ty][tx]      = tvs[0];
    redd[ty + 16][tx] = tvs[1];
    __syncthreads();
    if (t < 32) {
        double s = 0.0;
#pragma unroll
        for (int x = 0; x < 16; ++x) s += redd[t][x];
        atomicAdd(&TV[rowflat + t], s);
    }
}

// -------------------------------------------------------------------------
// Kernel C: gates from (T,TV,D,V), then out[b,f,:] = sum_p gate_p * xf[i_p,:]
// grid (900, 8) x 128 threads.
// -------------------------------------------------------------------------
__global__ __launch_bounds__(128) void gate_out_kernel(
    const float* __restrict__ xf, const float* __restrict__ V,
    const double* __restrict__ T, const double* __restrict__ TV,
    const float* __restrict__ D, float* __restrict__ out)
{
    const int f = blockIdx.x;
    const int b = blockIdx.y;
    const int fi = f / CH_O, fj = f % CH_O;
    const int t = threadIdx.x;

    __shared__ float gates[9];

    if (t < 9) {
        const int pr = t / 3, pc = t % 3;
        const int ip = (fi + pr) * W_IMG + (fj + pc);
        double se = 0.0, sev = 0.0;
#pragma unroll
        for (int q = 0; q < 9; ++q) {
            int qr = q / 3, qc = q % 3;
            float e = D[(b * HW_N + ip) * 25 + (qr - pr + 2) * 5 + (qc - pc + 2)];
            se += (double)e;
            float ev = e * V[b * HW_N + (fi + qr) * W_IMG + (fj + qc)];
            sev += (double)ev;
        }
        double denom = T[b * HW_N + ip] - se + 1e-5;
        double numer = TV[b * HW_N + ip] - sev;
        gates[t] = (float)(numer / denom);
    }
    __syncthreads();

    float o = 0.f;
#pragma unroll
    for (int p = 0; p < 9; ++p) {
        int ip = (fi + p / 3) * W_IMG + (fj + p % 3);
        o += gates[p] * xf[(b * HW_N + ip) * CD + t];
    }
    out[((b * F_N) + f) * CD + t] = o;
}

// -------------------------------------------------------------------------
extern "C" void kernel_launch(void* const* d_in, const int* in_sizes, int n_in,
                              void* d_out, int out_size, void* d_ws, size_t ws_size,
                              hipStream_t stream)
{
    (void)in_sizes; (void)n_in; (void)out_size; (void)ws_size;
    const float* batch = (const float*)d_in[0];
    const float* Wq    = (const float*)d_in[1];
    const float* bq    = (const float*)d_in[2];
    const float* Wk    = (const float*)d_in[3];
    const float* bk    = (const float*)d_in[4];
    const float* wv    = (const float*)d_in[5];
    const float* bv    = (const float*)d_in[6];
    // d_in[7] gmask, d_in[8] local_indices: not needed (structure recomputed)

    char*   ws = (char*)d_ws;
    float*  Q  = (float*)(ws + OFF_Q);
    float*  Kf = (float*)(ws + OFF_K);
    float*  V  = (float*)(ws + OFF_V);
    float*  D  = (float*)(ws + OFF_D);
    double* T  = (double*)(ws + OFF_T);
    double* TV = (double*)(ws + OFF_TV);
    float*  out = (float*)d_out;

    // zero the atomic accumulators (T and TV are contiguous)
    hipMemsetAsync(T, 0, 2 * BATCH * HW_N * sizeof(double), stream);

    qkv_kernel<<<dim3(256), dim3(256), 0, stream>>>(batch, Wq, bq, Wk, bk, wv, bv,
                                                    Q, Kf, V);
    attn_s_kernel<<<dim3(BATCH, 32, 4), dim3(256), 0, stream>>>(Q, Kf, V, T, TV, D);
    gate_out_kernel<<<dim3(F_N, BATCH), dim3(128), 0, stream>>>(batch, V, T, TV, D, out);
}

// Round 2
// 118.720 us; speedup vs baseline: 1.3416x; 1.3416x over previous
//
#include <hip/hip_runtime.h>

// Problem constants
#define BATCH 8
#define HW_N  1024   // 32*32
#define CD    128    // channels
#define W_IMG 32
#define CH_O  30
#define F_N   900    // 30*30

// Workspace layout (bytes)
#define OFF_QH 0u
#define OFF_QL 2097152u
#define OFF_KH 4194304u
#define OFF_KL 6291456u
#define OFF_V  8388608u
#define OFF_D  8421376u   // 8192*25*4 = 819200
#define OFF_T  9240576u   // 8192 doubles
#define OFF_TV 9306112u
// total 9371648 bytes

typedef __bf16 bf16x8 __attribute__((ext_vector_type(8)));
typedef float  f32x4  __attribute__((ext_vector_type(4)));

// -------------------------------------------------------------------------
// Kernel A: Q = xf@Wq^T + bq ; K = xf@Wk^T + bk ; V = xf@wv + bv
// Emits bf16 split pairs (Qh,Ql),(Kh,Kl) for the MFMA attn kernel.
// grid 256 blocks x 256 threads; each block does 32 rows.
// -------------------------------------------------------------------------
__global__ __launch_bounds__(256) void qkv_kernel(
    const float* __restrict__ xf,
    const float* __restrict__ Wq, const float* __restrict__ bq,
    const float* __restrict__ Wk, const float* __restrict__ bk,
    const float* __restrict__ wv, const float* __restrict__ bv,
    __bf16* __restrict__ Qh, __bf16* __restrict__ Ql,
    __bf16* __restrict__ Kh, __bf16* __restrict__ Kl,
    float* __restrict__ V)
{
    __shared__ float xs[32][132];
    __shared__ float wqs[32][132];
    __shared__ float wks[32][132];
    const int t = threadIdx.x;
    const int rowbase = blockIdx.x * 32;

#pragma unroll
    for (int m = 0; m < 4; ++m) {
        int id = t + 256 * m;
        int r  = id >> 5;
        int kq = id & 31;
        *(float4*)&xs[r][kq * 4] =
            *(const float4*)&xf[(size_t)(rowbase + r) * CD + kq * 4];
    }

    const int tx = t & 15, ty = t >> 4;

    for (int cc = 0; cc < 4; ++cc) {
        __syncthreads();
#pragma unroll
        for (int m = 0; m < 4; ++m) {
            int id = t + 256 * m;
            int r  = id >> 5;
            int kq = id & 31;
            *(float4*)&wqs[r][kq * 4] =
                *(const float4*)&Wq[(size_t)(cc * 32 + r) * CD + kq * 4];
            *(float4*)&wks[r][kq * 4] =
                *(const float4*)&Wk[(size_t)(cc * 32 + r) * CD + kq * 4];
        }
        __syncthreads();

        float aq[2][2], ak[2][2];
#pragma unroll
        for (int j = 0; j < 2; ++j)
#pragma unroll
            for (int m = 0; m < 2; ++m) { aq[j][m] = 0.f; ak[j][m] = 0.f; }

#pragma unroll 8
        for (int k = 0; k < CD; k += 4) {
            float4 x[2], q[2], kk[2];
            x[0]  = *(const float4*)&xs[ty][k];
            x[1]  = *(const float4*)&xs[ty + 16][k];
            q[0]  = *(const float4*)&wqs[tx][k];
            q[1]  = *(const float4*)&wqs[tx + 16][k];
            kk[0] = *(const float4*)&wks[tx][k];
            kk[1] = *(const float4*)&wks[tx + 16][k];
#pragma unroll
            for (int j = 0; j < 2; ++j)
#pragma unroll
                for (int m = 0; m < 2; ++m) {
                    aq[j][m] += x[j].x * q[m].x + x[j].y * q[m].y +
                                x[j].z * q[m].z + x[j].w * q[m].w;
                    ak[j][m] += x[j].x * kk[m].x + x[j].y * kk[m].y +
                                x[j].z * kk[m].z + x[j].w * kk[m].w;
                }
        }

#pragma unroll
        for (int j = 0; j < 2; ++j)
#pragma unroll
            for (int m = 0; m < 2; ++m) {
                int r = ty + 16 * j;
                int c = cc * 32 + tx + 16 * m;
                size_t o = (size_t)(rowbase + r) * CD + c;
                float qv = aq[j][m] + bq[c];
                float kv = ak[j][m] + bk[c];
                __bf16 qh = (__bf16)qv; float qhf = (float)qh;
                __bf16 ql = (__bf16)(qv - qhf);
                __bf16 khv = (__bf16)kv; float khf = (float)khv;
                __bf16 klv = (__bf16)(kv - khf);
                Qh[o] = qh;  Ql[o] = ql;
                Kh[o] = khv; Kl[o] = klv;
            }
    }

    __syncthreads();
    if (t < 32) {
        float s = 0.f;
#pragma unroll 8
        for (int k = 0; k < CD; ++k) s += xs[t][k] * wv[k];
        V[rowbase + t] = s + bv[0];
    }
}

// -------------------------------------------------------------------------
// Kernel B: S = Q@K^T via bf16 MFMA 3-term split; fused exp, row sums,
// banded E store. grid (8 batch, 8 rowblk, 8 colblk), 256 threads = 4 waves
// in 2x2; per-wave 64x64 (4x4 frags of 16x16x32). Dynamic LDS 74240 B.
// -------------------------------------------------------------------------
#define A_LDS_H 0
#define A_LDS_L 18432
#define B_LDS_H 36864
#define B_LDS_L 55296
#define VS_LDS  73728
#define ATTN_LDS_TOTAL 74240
#define SCR_TV_OFF 16896

__global__ __launch_bounds__(256, 2) void attn_kernel(
    const __bf16* __restrict__ Qh, const __bf16* __restrict__ Ql,
    const __bf16* __restrict__ Kh, const __bf16* __restrict__ Kl,
    const float* __restrict__ V,
    double* __restrict__ T, double* __restrict__ TV,
    float* __restrict__ D)
{
    extern __shared__ char lds[];
    __bf16* Ah = (__bf16*)(lds + A_LDS_H);
    __bf16* Al = (__bf16*)(lds + A_LDS_L);
    __bf16* Bh = (__bf16*)(lds + B_LDS_H);
    __bf16* Bl = (__bf16*)(lds + B_LDS_L);
    float*  Vs = (float*)(lds + VS_LDS);

    const int b  = blockIdx.x;
    const int rb = blockIdx.y;
    const int cb = blockIdx.z;
    const int t  = threadIdx.x;
    const int w    = t >> 6;
    const int lane = t & 63;
    const int q    = lane >> 4;   // quad
    const int i    = lane & 15;
    const int wy = w >> 1, wx = w & 1;

    if (t < 128) Vs[t] = V[b * HW_N + cb * 128 + t];

    f32x4 acc[4][4];
#pragma unroll
    for (int r = 0; r < 4; ++r)
#pragma unroll
        for (int f = 0; f < 4; ++f) acc[r][f] = (f32x4){0.f, 0.f, 0.f, 0.f};

    const size_t abase = (size_t)(b * HW_N + rb * 128) * CD;
    const size_t bbase = (size_t)(b * HW_N + cb * 128) * CD;

    for (int khalf = 0; khalf < 2; ++khalf) {
        __syncthreads();
#pragma unroll
        for (int m = 0; m < 4; ++m) {
            int id  = t + 256 * m;        // 0..1023
            int row = id >> 3;            // 0..127
            int c8  = id & 7;             // 8-bf16 chunk
            size_t gsrc = (size_t)row * CD + khalf * 64 + c8 * 8;
            int ldst = row * 72 + c8 * 8;
            *(f32x4*)&Ah[ldst] = *(const f32x4*)&Qh[abase + gsrc];
            *(f32x4*)&Al[ldst] = *(const f32x4*)&Ql[abase + gsrc];
            *(f32x4*)&Bh[ldst] = *(const f32x4*)&Kh[bbase + gsrc];
            *(f32x4*)&Bl[ldst] = *(const f32x4*)&Kl[bbase + gsrc];
        }
        __syncthreads();

#pragma unroll
        for (int kk = 0; kk < 2; ++kk) {
            bf16x8 ah[4], alr[4], bh4[4], bl4[4];
#pragma unroll
            for (int r = 0; r < 4; ++r) {
                int aoff = (wy * 64 + r * 16 + i) * 72 + kk * 32 + q * 8;
                ah[r]  = *(bf16x8*)&Ah[aoff];
                alr[r] = *(bf16x8*)&Al[aoff];
                int boff = (wx * 64 + r * 16 + i) * 72 + kk * 32 + q * 8;
                bh4[r] = *(bf16x8*)&Bh[boff];
                bl4[r] = *(bf16x8*)&Bl[boff];
            }
#pragma unroll
            for (int r = 0; r < 4; ++r)
#pragma unroll
                for (int f = 0; f < 4; ++f) {
                    acc[r][f] = __builtin_amdgcn_mfma_f32_16x16x32_bf16(
                        ah[r], bh4[f], acc[r][f], 0, 0, 0);
                    acc[r][f] = __builtin_amdgcn_mfma_f32_16x16x32_bf16(
                        ah[r], bl4[f], acc[r][f], 0, 0, 0);
                    acc[r][f] = __builtin_amdgcn_mfma_f32_16x16x32_bf16(
                        alr[r], bh4[f], acc[r][f], 0, 0, 0);
                }
        }
    }

    // ---- epilogue: exp, partial row sums, banded D store ----
    float st[4][4], stv[4][4];
#pragma unroll
    for (int r = 0; r < 4; ++r)
#pragma unroll
        for (int g = 0; g < 4; ++g) { st[r][g] = 0.f; stv[r][g] = 0.f; }

    const bool band = (cb - rb <= 1) && (rb - cb <= 1);

#pragma unroll
    for (int f = 0; f < 4; ++f) {
        int col_local = wx * 64 + f * 16 + i;
        int hw_c = cb * 128 + col_local;
        float v = Vs[col_local];
        int cimg_r = hw_c >> 5, cimg_c = hw_c & 31;
#pragma unroll
        for (int r = 0; r < 4; ++r)
#pragma unroll
            for (int g = 0; g < 4; ++g) {
                float e = __expf(acc[r][f][g]);
                st[r][g]  += e;
                stv[r][g] += e * v;
                if (band) {
                    int row_local = wy * 64 + r * 16 + q * 4 + g;
                    int hw_r = rb * 128 + row_local;
                    int dy = cimg_r - (hw_r >> 5);
                    int dx = cimg_c - (hw_r & 31);
                    if ((unsigned)(dy + 2) <= 4u && (unsigned)(dx + 2) <= 4u)
                        D[(size_t)(b * HW_N + hw_r) * 25 + (dy + 2) * 5 + (dx + 2)] = e;
                }
            }
    }

    // ---- block reduction (scratch aliases A-tile LDS) + double atomics ----
    __syncthreads();                 // all LDS frag reads complete
    float* scrT  = (float*)lds;              // 128 x 33 fp32
    float* scrTV = (float*)(lds + SCR_TV_OFF);
#pragma unroll
    for (int r = 0; r < 4; ++r)
#pragma unroll
        for (int g = 0; g < 4; ++g) {
            int row_local = wy * 64 + r * 16 + q * 4 + g;
            scrT [row_local * 33 + wx * 16 + i] = st[r][g];
            scrTV[row_local * 33 + wx * 16 + i] = stv[r][g];
        }
    __syncthreads();
    if (t < 128) {
        double s = 0.0;
#pragma unroll
        for (int c = 0; c < 32; ++c) s += (double)scrT[t * 33 + c];
        atomicAdd(&T[b * HW_N + rb * 128 + t], s);
    } else {
        int tt = t - 128;
        double s = 0.0;
#pragma unroll
        for (int c = 0; c < 32; ++c) s += (double)scrTV[tt * 33 + c];
        atomicAdd(&TV[b * HW_N + rb * 128 + tt], s);
    }
}

// -------------------------------------------------------------------------
// Kernel C: gates from (T,TV,D,V), out[b,fi,fj,:] = sum_p gate_p * xf[i_p,:]
// grid (30, 8) x 256 threads; xf rows staged in LDS (9x reuse).
// -------------------------------------------------------------------------
__global__ __launch_bounds__(256) void gate_out_kernel(
    const float* __restrict__ xf, const float* __restrict__ V,
    const double* __restrict__ T, const double* __restrict__ TV,
    const float* __restrict__ D, float* __restrict__ out)
{
    const int fi = blockIdx.x;   // 0..29
    const int b  = blockIdx.y;
    const int t  = threadIdx.x;

    __shared__ float xs[96 * 128];   // 3 img rows x 32 cols x 128 ch
    __shared__ float gates[30][9];

#pragma unroll
    for (int m = 0; m < 12; ++m) {
        int id   = t + 256 * m;      // float4 units, 0..3071
        int srow = id >> 5;          // 0..95
        int c4   = id & 31;
        int r3   = srow >> 5, colc = srow & 31;
        *(float4*)&xs[srow * 128 + c4 * 4] =
            *(const float4*)&xf[((size_t)(b * 32 + fi + r3) * 32 + colc) * CD + c4 * 4];
    }

    for (int g = t; g < 270; g += 256) {
        int fj = g / 9, p = g % 9;
        int pr = p / 3, pc = p % 3;
        int ip = (fi + pr) * W_IMG + (fj + pc);
        const float* Drow = &D[(size_t)(b * HW_N + ip) * 25];
        double se = 0.0, sev = 0.0;
#pragma unroll
        for (int qq = 0; qq < 9; ++qq) {
            int qr = qq / 3, qc = qq % 3;
            float e = Drow[(qr - pr + 2) * 5 + (qc - pc + 2)];
            se  += (double)e;
            sev += (double)(e * V[b * HW_N + (fi + qr) * W_IMG + (fj + qc)]);
        }
        double denom = T[b * HW_N + ip] - se + 1e-5;
        double numer = TV[b * HW_N + ip] - sev;
        gates[fj][p] = (float)(numer / denom);
    }
    __syncthreads();

    const int c   = t & 127;
    const int fjg = t >> 7;
#pragma unroll
    for (int it = 0; it < 15; ++it) {
        int fj = fjg * 15 + it;
        float o = 0.f;
#pragma unroll
        for (int p = 0; p < 9; ++p) {
            int pr = p / 3, pc = p % 3;
            o += gates[fj][p] * xs[(pr * 32 + fj + pc) * 128 + c];
        }
        out[((size_t)(b * F_N) + fi * CH_O + fj) * CD + c] = o;
    }
}

// -------------------------------------------------------------------------
extern "C" void kernel_launch(void* const* d_in, const int* in_sizes, int n_in,
                              void* d_out, int out_size, void* d_ws, size_t ws_size,
                              hipStream_t stream)
{
    (void)in_sizes; (void)n_in; (void)out_size; (void)ws_size;
    const float* batch = (const float*)d_in[0];
    const float* Wq    = (const float*)d_in[1];
    const float* bq    = (const float*)d_in[2];
    const float* Wk    = (const float*)d_in[3];
    const float* bk    = (const float*)d_in[4];
    const float* wv    = (const float*)d_in[5];
    const float* bv    = (const float*)d_in[6];

    char*    ws = (char*)d_ws;
    __bf16*  Qh = (__bf16*)(ws + OFF_QH);
    __bf16*  Ql = (__bf16*)(ws + OFF_QL);
    __bf16*  Kh = (__bf16*)(ws + OFF_KH);
    __bf16*  Kl = (__bf16*)(ws + OFF_KL);
    float*   V  = (float*)(ws + OFF_V);
    float*   D  = (float*)(ws + OFF_D);
    double*  T  = (double*)(ws + OFF_T);
    double*  TV = (double*)(ws + OFF_TV);
    float*   out = (float*)d_out;

    hipMemsetAsync(T, 0, 2 * BATCH * HW_N * sizeof(double), stream);

    qkv_kernel<<<dim3(256), dim3(256), 0, stream>>>(batch, Wq, bq, Wk, bk, wv, bv,
                                                    Qh, Ql, Kh, Kl, V);
    attn_kernel<<<dim3(8, 8, 8), dim3(256), ATTN_LDS_TOTAL, stream>>>(
        Qh, Ql, Kh, Kl, V, T, TV, D);
    gate_out_kernel<<<dim3(CH_O, BATCH), dim3(256), 0, stream>>>(batch, V, T, TV, D, out);
}